// Round 2
// baseline (4277.195 us; speedup 1.0000x reference)
//
#include <hip/hip_runtime.h>

#define BB  2
#define SS  4096
#define NN  16
#define HH  64
#define GSZ 128

// One thread = one query row; online softmax over [global GS keys] ++ [segment keys].
// All float tensors are f32 on device (verified: in_npz 95MB ~= f32 Q+K+V).
__global__ __launch_bounds__(256, 2) void mmattn_kernel(
    const void* __restrict__ modal_index, int nseg,
    const float* __restrict__ Q, const float* __restrict__ K, const float* __restrict__ V,
    const float* __restrict__ LM, const int* __restrict__ hasg_p,
    const float* __restrict__ GK, const float* __restrict__ GV, const float* __restrict__ GM,
    float* __restrict__ Out)
{
    const int b = blockIdx.z;
    const int n = blockIdx.y;
    const int s = blockIdx.x * 256 + threadIdx.x;   // query position

    // ---- segment lookup; tolerate int32 OR int64 modal_index on device ----
    const int*       p32 = (const int*)modal_index;
    const long long* p64 = (const long long*)modal_index;
    const bool is32 = (p32[2 * nseg - 1] == SS);
    int st = 0, en = SS;
    for (int i = 0; i < nseg; ++i) {
        int a = is32 ? p32[2 * i]     : (int)p64[2 * i];
        int c = is32 ? p32[2 * i + 1] : (int)p64[2 * i + 1];
        if (s >= a && s < c) { st = a; en = c; }
    }

    const float scale = 0.125f;   // 1/sqrt(64)

    // ---- q row into registers ----
    float q[HH];
    {
        const float4* qrow = (const float4*)(Q + ((size_t)((b * SS + s) * NN + n)) * HH);
        #pragma unroll
        for (int i = 0; i < HH / 4; ++i) {
            float4 d = qrow[i];
            q[4*i+0] = d.x; q[4*i+1] = d.y; q[4*i+2] = d.z; q[4*i+3] = d.w;
        }
    }

    float o[HH];
    #pragma unroll
    for (int h = 0; h < HH; ++h) o[h] = 0.f;
    float m = -3.0e38f, l = 0.f;

    auto process = [&](const float4* kr, const float4* vr, float maskv) {
        float d0 = 0.f, d1 = 0.f, d2 = 0.f, d3 = 0.f;
        #pragma unroll
        for (int i = 0; i < HH / 4; ++i) {
            float4 kv = kr[i];
            d0 = fmaf(kv.x, q[4*i+0], d0);
            d1 = fmaf(kv.y, q[4*i+1], d1);
            d2 = fmaf(kv.z, q[4*i+2], d2);
            d3 = fmaf(kv.w, q[4*i+3], d3);
        }
        float sc = ((d0 + d1) + (d2 + d3)) * scale + maskv;
        if (sc > m) {                      // divergent but rare after warm-up
            float corr = __expf(m - sc);   // exp(-huge)=0 on first key
            l *= corr;
            #pragma unroll
            for (int h = 0; h < HH; ++h) o[h] *= corr;
            m = sc;
        }
        float p = __expf(sc - m);
        l += p;
        #pragma unroll
        for (int i = 0; i < HH / 4; ++i) {
            float4 vv = vr[i];
            o[4*i+0] = fmaf(p, vv.x, o[4*i+0]);
            o[4*i+1] = fmaf(p, vv.y, o[4*i+1]);
            o[4*i+2] = fmaf(p, vv.z, o[4*i+2]);
            o[4*i+3] = fmaf(p, vv.w, o[4*i+3]);
        }
    };

    // ---- global keys (wave-uniform rows -> broadcast loads) ----
    if (*hasg_p) {
        const float4* gk = (const float4*)(GK + ((size_t)(b * NN + n)) * GSZ * HH);
        const float4* gv = (const float4*)(GV + ((size_t)(b * NN + n)) * GSZ * HH);
        for (int g = 0; g < GSZ; ++g) {
            process(gk + g * (HH / 4), gv + g * (HH / 4), GM[b * GSZ + g]);
        }
    }

    // ---- local segment keys ----
    for (int j = st; j < en; ++j) {
        const float4* kr = (const float4*)(K + ((size_t)((b * SS + j) * NN + n)) * HH);
        const float4* vr = (const float4*)(V + ((size_t)((b * SS + j) * NN + n)) * HH);
        process(kr, vr, LM[b * SS + j]);
    }

    // ---- epilogue: normalize + 16B stores ----
    const float inv = 1.0f / l;
    float4* orow = (float4*)(Out + ((size_t)((b * SS + s) * NN + n)) * HH);
    #pragma unroll
    for (int i = 0; i < HH / 4; ++i) {
        float4 d;
        d.x = o[4*i+0] * inv; d.y = o[4*i+1] * inv;
        d.z = o[4*i+2] * inv; d.w = o[4*i+3] * inv;
        orow[i] = d;
    }
}

extern "C" void kernel_launch(void* const* d_in, const int* in_sizes, int n_in,
                              void* d_out, int out_size, void* d_ws, size_t ws_size,
                              hipStream_t stream)
{
    const void* modal = d_in[0];
    const int   nseg  = in_sizes[0] / 2;
    const float* Q  = (const float*)d_in[1];
    const float* K  = (const float*)d_in[2];
    const float* V  = (const float*)d_in[3];
    const float* LM = (const float*)d_in[4];
    const int*   HG = (const int*)d_in[5];
    const float* GK = (const float*)d_in[6];
    const float* GV = (const float*)d_in[7];
    const float* GM = (const float*)d_in[8];
    float* Out = (float*)d_out;

    dim3 grid(SS / 256, NN, BB);
    mmattn_kernel<<<grid, dim3(256), 0, stream>>>(modal, nseg, Q, K, V, LM, HG, GK, GV, GM, Out);
}

// Round 5
// 394.023 us; speedup vs baseline: 10.8552x; 10.8552x over previous
//
#include <hip/hip_runtime.h>

typedef unsigned int u32;
typedef unsigned short u16;
typedef __attribute__((ext_vector_type(8))) short bf16x8;
typedef __attribute__((ext_vector_type(4))) float f32x4;

#define BB 2
#define SS 4096
#define NN 16
#define HH 64
#define GSZ 128
#define QT 64          // queries per block (4 waves x 16)
#define KT 64          // keys per tile
#define KP 72          // K_lds row pitch (bf16 elems)
#define VP 72          // V^T row pitch
#define PP 72          // P row pitch
#define SCALE 0.125f

__device__ __forceinline__ u16 f2bf(float f){
    u32 x = __float_as_uint(f);
    return (u16)((x + 0x7fffu + ((x >> 16) & 1u)) >> 16);   // RNE
}
__device__ __forceinline__ u32 pk2(float a, float b){
    return (u32)f2bf(a) | ((u32)f2bf(b) << 16);
}

__global__ __launch_bounds__(256, 2) void mmattn_mfma(
    const void* __restrict__ modal_index, int nseg,
    const float* __restrict__ Q, const float* __restrict__ K, const float* __restrict__ V,
    const float* __restrict__ LM, const int* __restrict__ hasg_p,
    const float* __restrict__ GK, const float* __restrict__ GV, const float* __restrict__ GM,
    float* __restrict__ Out)
{
    __shared__ u16 Klds[KT * KP];       // [key][h]   row-major bf16
    __shared__ u16 Vt  [HH * VP];       // [h][key]   transposed bf16
    __shared__ u16 Pl  [4 * 16 * PP];   // per-wave [qrow][key] bf16

    const int b = blockIdx.z, n = blockIdx.y;
    const int q0 = blockIdx.x * QT;
    const int tid  = threadIdx.x;
    const int wid  = tid >> 6, lane = tid & 63;
    const int lr   = lane & 15, lg = lane >> 4;

    // ---- segment lookup (int32 or int64 modal_index) ----
    const int*       p32 = (const int*)modal_index;
    const long long* p64 = (const long long*)modal_index;
    const bool is32 = (p32[2 * nseg - 1] == SS);
    int st = 0, en = SS;
    for (int i = 0; i < nseg; ++i) {
        int a = is32 ? p32[2*i]   : (int)p64[2*i];
        int c = is32 ? p32[2*i+1] : (int)p64[2*i+1];
        if (q0 >= a && q0 < c) { st = a; en = c; }
    }

    // ---- Q fragments (A-layout: row=lr, k = chunk*32 + lg*8 + i) ----
    bf16x8 qa0, qa1;
    {
        const float* qp = Q + (((size_t)(b * SS + q0 + wid * 16 + lr)) * NN + n) * HH + lg * 8;
        float4 f0 = *(const float4*)(qp);
        float4 f1 = *(const float4*)(qp + 4);
        float4 f2 = *(const float4*)(qp + 32);
        float4 f3 = *(const float4*)(qp + 36);
        union { u32 w[4]; bf16x8 v; } ua, ub;
        ua.w[0]=pk2(f0.x,f0.y); ua.w[1]=pk2(f0.z,f0.w); ua.w[2]=pk2(f1.x,f1.y); ua.w[3]=pk2(f1.z,f1.w);
        ub.w[0]=pk2(f2.x,f2.y); ub.w[1]=pk2(f2.z,f2.w); ub.w[2]=pk2(f3.x,f3.y); ub.w[3]=pk2(f3.z,f3.w);
        qa0 = ua.v; qa1 = ub.v;
    }

    f32x4 o[4];
    #pragma unroll
    for (int hb = 0; hb < 4; ++hb) { o[hb][0]=0.f; o[hb][1]=0.f; o[hb][2]=0.f; o[hb][3]=0.f; }
    float m[4] = {-1e30f,-1e30f,-1e30f,-1e30f};
    float l[4] = {0.f,0.f,0.f,0.f};

    const int sr  = tid >> 2;      // staging: key row 0..63
    const int scq = tid & 3;       // staging: col quarter

    auto tile = [&](const float* kb_, const float* vb_, size_t rs, const float* mp) {
        // ---- stage K (row-major) and V^T into LDS as bf16 ----
        {
            const float* kp = kb_ + (size_t)sr * rs + scq * 16;
            float4 k0 = *(const float4*)(kp);
            float4 k1 = *(const float4*)(kp + 4);
            float4 k2 = *(const float4*)(kp + 8);
            float4 k3 = *(const float4*)(kp + 12);
            uint4* kd = (uint4*)&Klds[sr * KP + scq * 16];
            kd[0] = make_uint4(pk2(k0.x,k0.y), pk2(k0.z,k0.w), pk2(k1.x,k1.y), pk2(k1.z,k1.w));
            kd[1] = make_uint4(pk2(k2.x,k2.y), pk2(k2.z,k2.w), pk2(k3.x,k3.y), pk2(k3.z,k3.w));

            const float* vp = vb_ + (size_t)sr * rs + scq * 16;
            float4 v0 = *(const float4*)(vp);
            float4 v1 = *(const float4*)(vp + 4);
            float4 v2 = *(const float4*)(vp + 8);
            float4 v3 = *(const float4*)(vp + 12);
            float vv[16] = {v0.x,v0.y,v0.z,v0.w, v1.x,v1.y,v1.z,v1.w,
                            v2.x,v2.y,v2.z,v2.w, v3.x,v3.y,v3.z,v3.w};
            #pragma unroll
            for (int j = 0; j < 16; ++j)
                Vt[(scq * 16 + j) * VP + sr] = f2bf(vv[j]);
        }
        __syncthreads();

        // ---- masks (per key column) ----
        float mk[4];
        #pragma unroll
        for (int cb = 0; cb < 4; ++cb) mk[cb] = mp[cb * 16 + lr];

        // ---- QK^T: S[cb] = Q(16x64) * K^T(64x16), D-layout rows=(lg*4+r) ----
        f32x4 s[4];
        #pragma unroll
        for (int cb = 0; cb < 4; ++cb) {
            const bf16x8 kb0 = *(const bf16x8*)&Klds[(cb*16 + lr) * KP + lg*8];
            const bf16x8 kb1 = *(const bf16x8*)&Klds[(cb*16 + lr) * KP + 32 + lg*8];
            f32x4 acc; acc[0]=0.f; acc[1]=0.f; acc[2]=0.f; acc[3]=0.f;
            acc = __builtin_amdgcn_mfma_f32_16x16x32_bf16(qa0, kb0, acc, 0, 0, 0);
            acc = __builtin_amdgcn_mfma_f32_16x16x32_bf16(qa1, kb1, acc, 0, 0, 0);
            s[cb] = acc;
        }

        // ---- online softmax (per D-layout row), write P to wave-local LDS ----
        float cr[4];
        #pragma unroll
        for (int r = 0; r < 4; ++r) {
            float s0 = s[0][r]*SCALE + mk[0];
            float s1 = s[1][r]*SCALE + mk[1];
            float s2 = s[2][r]*SCALE + mk[2];
            float s3 = s[3][r]*SCALE + mk[3];
            float mx = fmaxf(fmaxf(s0, s1), fmaxf(s2, s3));
            mx = fmaxf(mx, __shfl_xor(mx, 1));
            mx = fmaxf(mx, __shfl_xor(mx, 2));
            mx = fmaxf(mx, __shfl_xor(mx, 4));
            mx = fmaxf(mx, __shfl_xor(mx, 8));
            float nm = fmaxf(m[r], mx);
            float c_ = __expf(m[r] - nm);
            m[r] = nm;
            float p0 = __expf(s0 - nm), p1 = __expf(s1 - nm);
            float p2 = __expf(s2 - nm), p3 = __expf(s3 - nm);
            float rsum = ((p0 + p1) + (p2 + p3));
            rsum += __shfl_xor(rsum, 1);
            rsum += __shfl_xor(rsum, 2);
            rsum += __shfl_xor(rsum, 4);
            rsum += __shfl_xor(rsum, 8);
            l[r] = l[r] * c_ + rsum;
            cr[r] = c_;
            u16* pw = &Pl[wid * 16 * PP + (lg * 4 + r) * PP + lr];
            pw[0]  = f2bf(p0); pw[16] = f2bf(p1);
            pw[32] = f2bf(p2); pw[48] = f2bf(p3);
        }
        #pragma unroll
        for (int hb = 0; hb < 4; ++hb) {
            o[hb][0]*=cr[0]; o[hb][1]*=cr[1]; o[hb][2]*=cr[2]; o[hb][3]*=cr[3];
        }

        // ---- PV: O += P(16x64) * V(64x64); P re-read in A-layout ----
        const bf16x8 pa0 = *(const bf16x8*)&Pl[wid*16*PP + lr*PP + lg*8];
        const bf16x8 pa1 = *(const bf16x8*)&Pl[wid*16*PP + lr*PP + 32 + lg*8];
        #pragma unroll
        for (int hb = 0; hb < 4; ++hb) {
            const bf16x8 vb0 = *(const bf16x8*)&Vt[(hb*16 + lr) * VP + lg*8];
            const bf16x8 vb1 = *(const bf16x8*)&Vt[(hb*16 + lr) * VP + 32 + lg*8];
            o[hb] = __builtin_amdgcn_mfma_f32_16x16x32_bf16(pa0, vb0, o[hb], 0, 0, 0);
            o[hb] = __builtin_amdgcn_mfma_f32_16x16x32_bf16(pa1, vb1, o[hb], 0, 0, 0);
        }
        __syncthreads();   // protect Klds/Vt before next staging
    };

    // ---- global key tiles first (order within softmax concat is irrelevant) ----
    if (*hasg_p) {
        const float* gkb = GK + ((size_t)(b * NN + n)) * GSZ * HH;
        const float* gvb = GV + ((size_t)(b * NN + n)) * GSZ * HH;
        const float* gmb = GM + (size_t)b * GSZ;
        tile(gkb,            gvb,            HH, gmb);
        tile(gkb + 64 * HH,  gvb + 64 * HH,  HH, gmb + 64);
    }
    // ---- local segment tiles ----
    {
        const float* lmb = LM + (size_t)b * SS;
        for (int k0 = st; k0 < en; k0 += KT) {
            const float* kb_ = K + (((size_t)(b * SS + k0)) * NN + n) * HH;
            const float* vb_ = V + (((size_t)(b * SS + k0)) * NN + n) * HH;
            tile(kb_, vb_, (size_t)NN * HH, lmb + k0);
        }
    }

    // ---- epilogue ----
    float inv[4] = {1.f/l[0], 1.f/l[1], 1.f/l[2], 1.f/l[3]};
    #pragma unroll
    for (int hb = 0; hb < 4; ++hb) {
        #pragma unroll
        for (int r = 0; r < 4; ++r) {
            const int qrow = q0 + wid * 16 + lg * 4 + r;
            Out[(((size_t)(b * SS + qrow)) * NN + n) * HH + hb * 16 + lr] = o[hb][r] * inv[r];
        }
    }
}

extern "C" void kernel_launch(void* const* d_in, const int* in_sizes, int n_in,
                              void* d_out, int out_size, void* d_ws, size_t ws_size,
                              hipStream_t stream)
{
    const void* modal = d_in[0];
    const int   nseg  = in_sizes[0] / 2;
    const float* Q  = (const float*)d_in[1];
    const float* K  = (const float*)d_in[2];
    const float* V  = (const float*)d_in[3];
    const float* LM = (const float*)d_in[4];
    const int*   HG = (const int*)d_in[5];
    const float* GK = (const float*)d_in[6];
    const float* GV = (const float*)d_in[7];
    const float* GM = (const float*)d_in[8];
    float* Out = (float*)d_out;

    dim3 grid(SS / QT, NN, BB);
    mmattn_mfma<<<grid, dim3(256), 0, stream>>>(modal, nseg, Q, K, V, LM, HG, GK, GV, GM, Out);
}